// Round 6
// baseline (355.072 us; speedup 1.0000x reference)
//
#include <hip/hip_runtime.h>
#include <hip/hip_bf16.h>
#include <hip/hip_cooperative_groups.h>

namespace cg = cooperative_groups;

// Problem constants
#define HH 256
#define WW 256
#define BB 4
#define CC 3
#define HW 65536          // H*W
#define NM 24             // 2*B*C masks (0..11 lab, 12..23 pred)
#define BIGF 1e9f
#define LIMITF 331776.0f  // 576*576
#define EPSF 1e-5f

// ---------------------------------------------------------------------------
// Single cooperative kernel: 4 phases separated by grid.sync().
//  P1 rowpass : block (b,i) computes row-EDT^2 for all 6 masks of its row.
//  P2 colpass : blocks 0..767 do exact-windowed column min-plus in-place.
//  P3 final   : per-pixel cosine sim -> per-block partials (psum/pfg).
//  P4 reduce  : block 0 folds 1024 partials -> loss.
// Replaces 4 launches (3 inter-dispatch gaps) with 1 dispatch; all
// intermediates (dbuf 6MB) stay warm in L2/L3 across phases.
// grid: 1024 blocks x 256 threads (4 blocks/CU — co-residency guaranteed).
// ---------------------------------------------------------------------------
__global__ __launch_bounds__(256) void k_fused(const float* __restrict__ pred,
                                               const int* __restrict__ lab,
                                               float* __restrict__ dbuf,
                                               float* __restrict__ blkmax,
                                               float* __restrict__ psum,
                                               int* __restrict__ pfg,
                                               float* __restrict__ out) {
    cg::grid_group grid = cg::this_grid();
    __shared__ float tile[256 * 9];            // P2 column slab (9 KB)
    __shared__ unsigned long long zm[6][4];    // P1 zero-pixel bitmaps
    __shared__ float red_f[NM];                // P3 inv[] / P1-P4 small reduces
    __shared__ int   red_i[4];

    const int tid = threadIdx.x;
    const int blk = blockIdx.x;

    // ---------------- Phase 1: row-wise EDT^2 (exact) ----------------
    {
        int b = blk >> 8;
        int i = blk & 255;
        int j = tid;

        int lv = lab[(b << 16) + (i << 8) + j];
        const float* pb = pred + (((size_t)(b * 3)) << 16) + (i << 8) + j;
        float p0 = pb[0];
        float p1 = pb[(size_t)1 << 16];
        float p2 = pb[(size_t)2 << 16];
        int am = 0; float v = p0;
        if (p1 > v) { am = 1; v = p1; }
        if (p2 > v) { am = 2; }

        int w = tid >> 6;
        #pragma unroll
        for (int c = 0; c < 3; ++c) {
            unsigned long long zl = __ballot(lv != c);
            unsigned long long zp = __ballot(am != c);
            if ((tid & 63) == 0) { zm[c][w] = zl; zm[3 + c][w] = zp; }
        }
        __syncthreads();

        #pragma unroll
        for (int t = 0; t < 6; ++t) {
            int bestd = 512;  // sentinel > any possible distance (<=255)
            #pragma unroll
            for (int w2 = 0; w2 < 4; ++w2) {
                unsigned long long z = zm[t][w2];
                int base = w2 << 6;
                int rel = j - base;
                unsigned long long mle;   // bits at positions <= rel
                if (rel >= 63)      mle = ~0ULL;
                else if (rel < 0)   mle = 0ULL;
                else                mle = (2ULL << rel) - 1ULL;
                unsigned long long zl = z & mle;
                if (zl) {
                    int p = base + 63 - __clzll(zl);
                    int d = j - p;
                    if (d < bestd) bestd = d;
                }
                unsigned long long zr = z & ~mle;
                if (zr) {
                    int p = base + __ffsll(zr) - 1;
                    int d = p - j;
                    if (d < bestd) bestd = d;
                }
            }
            float d1 = (bestd >= 512) ? BIGF : (float)(bestd * bestd);
            int c = (t < 3) ? t : (t - 3);
            int m = ((t < 3) ? 0 : 12) + b * 3 + c;
            dbuf[(((size_t)m) << 16) + (i << 8) + j] = d1;
        }
    }

    grid.sync();

    // ------------- Phase 2: column min-plus, exact windowing -------------
    // Any |i-k| > sqrt(d1[i]) can't beat candidate k=i, so the window
    // [i-R, i+R], R = floor(sqrt(d1[i]))+1 (clamped; BIG -> full scan) is
    // exact. fma(dk,dk,d1[k]) bit-identical to reference (exact int square,
    // one rounding). Blocks own disjoint 8-column slabs: in-place safe.
    if (blk < NM * 32) {
        int m = blk >> 5;
        int j0 = (blk & 31) << 3;
        float* base = dbuf + (((size_t)m) << 16);

        #pragma unroll
        for (int it = 0; it < 2; ++it) {
            int f = (it << 8) + tid;       // float4 index 0..511
            int row = f >> 1, half = f & 1;
            float4 v4 = *(const float4*)(base + (row << 8) + j0 + (half << 2));
            int lb = row * 9 + (half << 2);
            tile[lb + 0] = v4.x; tile[lb + 1] = v4.y;
            tile[lb + 2] = v4.z; tile[lb + 3] = v4.w;
        }
        __syncthreads();

        int jj = tid & 7;
        int ib = tid >> 3;   // 0..31
        float lmax = 0.0f;

        #pragma unroll
        for (int r = 0; r < 8; ++r) {
            int i = ib + (r << 5);
            float di = tile[i * 9 + jj];
            float acc = di;                    // k = i candidate
            int R = (int)sqrtf(di) + 1;        // over-estimate: still exact
            if (R > 255) R = 255;              // BIG -> full scan
            int k0 = i - R; if (k0 < 0) k0 = 0;
            int k1 = i + R; if (k1 > 255) k1 = 255;
            for (int k = k0; k <= k1; ++k) {
                float dk = (float)(k - i);
                acc = fminf(acc, fmaf(dk, dk, tile[k * 9 + jj]));
            }
            base[(i << 8) + j0 + jj] = acc;
            lmax = fmaxf(lmax, acc);
        }

        #pragma unroll
        for (int off = 32; off; off >>= 1)
            lmax = fmaxf(lmax, __shfl_down(lmax, off, 64));
        if ((tid & 63) == 0) red_f[tid >> 6] = lmax;
        __syncthreads();
        if (tid == 0)
            blkmax[blk] = fmaxf(fmaxf(red_f[0], red_f[1]),
                                fmaxf(red_f[2], red_f[3]));
    }

    grid.sync();

    // ---------------- Phase 3: cosine sim -> block partials ----------------
    {
        if (tid < NM) {
            const float* bm = blkmax + (tid << 5);
            float v = 0.0f;
            #pragma unroll
            for (int s = 0; s < 32; ++s) v = fmaxf(v, bm[s]);
            red_f[tid] = 1.0f / (fminf(sqrtf(v), LIMITF) + EPSF);  // inv[m]
        }
        __syncthreads();

        int b = blk >> 8;                          // uniform per block
        int pix = ((blk & 255) << 8) + tid;

        int lv = lab[(b << 16) + pix];
        const float* pb = pred + (((size_t)(b * 3)) << 16) + pix;
        float p0 = pb[0];
        float p1 = pb[(size_t)1 << 16];
        float p2 = pb[(size_t)2 << 16];
        int am = 0; float v = p0;
        if (p1 > v) { am = 1; v = p1; }
        if (p2 > v) { am = 2; }

        float slab = 0.0f, spred = 0.0f;
        #pragma unroll
        for (int c = 0; c < 3; ++c) {
            int ml = b * 3 + c;
            float dl = dbuf[(((size_t)ml) << 16) + pix];
            slab += sqrtf(dl) * red_f[ml];
            float dp = dbuf[(((size_t)(ml + 12)) << 16) + pix];
            spred += sqrtf(dp) * red_f[ml + 12];
        }

        float dot = spred * slab + ((am == lv) ? 1.0f : 0.0f);
        float na = sqrtf(spred * spred + 1.0f);
        float nb = sqrtf(slab * slab + 1.0f);
        float sim = dot / (fmaxf(na, 1e-8f) * fmaxf(nb, 1e-8f));

        unsigned long long fg = __ballot(lv > 0);

        #pragma unroll
        for (int off = 32; off; off >>= 1)
            sim += __shfl_down(sim, off, 64);
        __syncthreads();   // red_f reuse (inv -> wave sums)
        if ((tid & 63) == 0) {
            red_f[tid >> 6] = sim;
            red_i[tid >> 6] = (fg != 0ULL) ? 1 : 0;
        }
        __syncthreads();
        if (tid == 0) {
            psum[blk] = red_f[0] + red_f[1] + red_f[2] + red_f[3];
            pfg[blk]  = red_i[0] | red_i[1] | red_i[2] | red_i[3];
        }
    }

    grid.sync();

    // ---------------- Phase 4: block 0 folds partials -> loss ----------------
    if (blk == 0) {
        int b = tid >> 6, l = tid & 63;
        int base = (b << 8) + l;
        float s = psum[base] + psum[base + 64] + psum[base + 128] + psum[base + 192];
        int f = pfg[base] | pfg[base + 64] | pfg[base + 128] | pfg[base + 192];
        #pragma unroll
        for (int off = 32; off; off >>= 1) {
            s += __shfl_down(s, off, 64);
            f |= __shfl_down(f, off, 64);
        }
        __syncthreads();   // red_f reuse
        if (l == 0) { red_f[b] = s; red_i[b] = f; }
        __syncthreads();
        if (tid == 0) {
            float loss = 0.0f;
            for (int bb = 0; bb < BB; ++bb) {
                float lb = 1.0f - red_f[bb] * (1.0f / (float)HW);
                if (red_i[bb]) loss += lb;
            }
            loss *= (1.0f / (float)BB);
            if (isnan(loss)) loss = 0.0f;
            else if (isinf(loss)) loss = (loss > 0.0f) ? 1.0f : 0.0f;
            out[0] = loss;
        }
    }
}

extern "C" void kernel_launch(void* const* d_in, const int* in_sizes, int n_in,
                              void* d_out, int out_size, void* d_ws, size_t ws_size,
                              hipStream_t stream) {
    const float* pred = (const float*)d_in[0];   // [4,3,256,256] f32
    const int*   lab  = (const int*)d_in[1];     // [4,256,256] i32
    float* outp = (float*)d_out;

    char* wsb = (char*)d_ws;
    float* dbuf   = (float*)wsb;                                  // 24*65536 f32 = 6 MB
    size_t off    = (size_t)NM * HW * sizeof(float);
    float* blkmax = (float*)(wsb + off);          off += 768 * sizeof(float);
    float* psum   = (float*)(wsb + off);          off += 1024 * sizeof(float);
    int*   pfg    = (int*)  (wsb + off);

    void* args[] = {(void*)&pred, (void*)&lab, (void*)&dbuf, (void*)&blkmax,
                    (void*)&psum, (void*)&pfg, (void*)&outp};
    hipLaunchCooperativeKernel((const void*)k_fused, dim3(BB * HH), dim3(256),
                               args, 0, stream);
}

// Round 7
// 91.219 us; speedup vs baseline: 3.8925x; 3.8925x over previous
//
#include <hip/hip_runtime.h>
#include <hip/hip_bf16.h>

// Problem constants
#define HH 256
#define WW 256
#define BB 4
#define CC 3
#define HW 65536          // H*W
#define NM 24             // 2*B*C masks (0..11 lab, 12..23 pred)
#define BIGF 1e9f
#define LIMITF 331776.0f  // 576*576
#define EPSF 1e-5f

// NOTE (R6 lesson): cooperative grid.sync() costs ~90us/sync at 1024 blocks
// on gfx950 (355us total vs 84us for 4 plain launches). Keep separate
// launches; a graph-replayed launch gap is ~2-3us.

// ---------------------------------------------------------------------------
// Pass 1: row-wise squared distance to nearest zero, all 6 masks of one
// (batch,row) per block. Stores RAW d1 (bit-exact vs reference row pass)
// plus a per-pixel code byte (lab | argmax<<2) so k_final never re-reads
// pred/lab (saves 4 MB of loads there).
// grid: 4*256 blocks (b,row), 256 threads (col).
// ---------------------------------------------------------------------------
__global__ __launch_bounds__(256) void k_rowpass(const float* __restrict__ pred,
                                                 const int* __restrict__ lab,
                                                 float* __restrict__ dbuf,
                                                 unsigned char* __restrict__ codes) {
    int blk = blockIdx.x;
    int b = blk >> 8;
    int i = blk & 255;
    int j = threadIdx.x;

    int lv = lab[(b << 16) + (i << 8) + j];
    const float* pb = pred + (((size_t)(b * 3)) << 16) + (i << 8) + j;
    float p0 = pb[0];
    float p1 = pb[(size_t)1 << 16];
    float p2 = pb[(size_t)2 << 16];
    int am = 0; float v = p0;
    if (p1 > v) { am = 1; v = p1; }
    if (p2 > v) { am = 2; }

    codes[(b << 16) + (i << 8) + j] = (unsigned char)(lv | (am << 2));

    __shared__ unsigned long long zm[6][4];   // [mask][wave] zero-pixel bitmaps
    int w = threadIdx.x >> 6;
    #pragma unroll
    for (int c = 0; c < 3; ++c) {
        unsigned long long zl = __ballot(lv != c);
        unsigned long long zp = __ballot(am != c);
        if ((threadIdx.x & 63) == 0) { zm[c][w] = zl; zm[3 + c][w] = zp; }
    }
    __syncthreads();

    #pragma unroll
    for (int t = 0; t < 6; ++t) {
        int bestd = 512;  // sentinel > any possible distance (<=255)
        #pragma unroll
        for (int w2 = 0; w2 < 4; ++w2) {
            unsigned long long z = zm[t][w2];
            int base = w2 << 6;
            int rel = j - base;
            unsigned long long mle;   // bits at positions <= rel
            if (rel >= 63)      mle = ~0ULL;
            else if (rel < 0)   mle = 0ULL;
            else                mle = (2ULL << rel) - 1ULL;
            unsigned long long zl = z & mle;
            if (zl) {
                int p = base + 63 - __clzll(zl);
                int d = j - p;
                if (d < bestd) bestd = d;
            }
            unsigned long long zr = z & ~mle;
            if (zr) {
                int p = base + __ffsll(zr) - 1;
                int d = p - j;
                if (d < bestd) bestd = d;
            }
        }
        float d1 = (bestd >= 512) ? BIGF : (float)(bestd * bestd);
        int c = (t < 3) ? t : (t - 3);
        int m = ((t < 3) ? 0 : 12) + b * 3 + c;
        dbuf[(((size_t)m) << 16) + (i << 8) + j] = d1;
    }
}

// ---------------------------------------------------------------------------
// Pass 2: column-wise min-plus with EXACT windowing:
//   d[i,j] = min_k d1[k,j]+(i-k)^2.
// Window [i-R, i+R], R = floor(sqrt(d1[i]))+1 is exact (k=i is a candidate,
// d1>=0); BIG rows clamp to the full 256-scan. fma(dk,dk,d1[k]) bit-identical
// to reference. One block owns 32 FULL columns (in-place safe): 128 B per
// row = whole cache lines, fixing the 4x over-fetch of 8-wide slabs
// (R3/R6 counters: 24.6/17.7 MB FETCH for a 6 MB buffer). Stride-33 pad.
// grid: 24*8 blocks, 256 threads.
// ---------------------------------------------------------------------------
__global__ __launch_bounds__(256) void k_colpass(float* __restrict__ dbuf,
                                                 float* __restrict__ blkmax) {
    int blk = blockIdx.x;
    int m = blk >> 3;
    int j0 = (blk & 7) << 5;
    __shared__ float tile[256 * 33];   // [row][jj], stride 33, 33 KB
    float* base = dbuf + (((size_t)m) << 16);

    // Stage 256x32 slab via float4 (8 per thread) — full 128 B lines.
    #pragma unroll
    for (int it = 0; it < 8; ++it) {
        int f = (it << 8) + threadIdx.x;   // float4 index 0..2047
        int row = f >> 3, quad = f & 7;
        float4 v = *(const float4*)(base + (row << 8) + j0 + (quad << 2));
        int lb = row * 33 + (quad << 2);
        tile[lb + 0] = v.x; tile[lb + 1] = v.y;
        tile[lb + 2] = v.z; tile[lb + 3] = v.w;
    }
    __syncthreads();

    int jj = threadIdx.x & 31;
    int ib = threadIdx.x >> 5;   // 0..7
    float lmax = 0.0f;

    #pragma unroll
    for (int r = 0; r < 32; ++r) {
        int i = ib + (r << 3);
        float di = tile[i * 33 + jj];
        float acc = di;                    // k = i candidate
        int R = (int)sqrtf(di) + 1;        // over-estimate is still exact
        if (R > 255) R = 255;              // BIG -> full scan
        int k0 = i - R; if (k0 < 0) k0 = 0;
        int k1 = i + R; if (k1 > 255) k1 = 255;
        for (int k = k0; k <= k1; ++k) {
            float dk = (float)(k - i);
            acc = fminf(acc, fmaf(dk, dk, tile[k * 33 + jj]));
        }
        base[(i << 8) + j0 + jj] = acc;    // wave: 2 full 128 B lines
        lmax = fmaxf(lmax, acc);
    }

    #pragma unroll
    for (int off = 32; off; off >>= 1)
        lmax = fmaxf(lmax, __shfl_down(lmax, off, 64));
    __shared__ float wmax[4];
    if ((threadIdx.x & 63) == 0) wmax[threadIdx.x >> 6] = lmax;
    __syncthreads();
    if (threadIdx.x == 0)
        blkmax[blk] = fmaxf(fmaxf(wmax[0], wmax[1]), fmaxf(wmax[2], wmax[3]));
}

// ---------------------------------------------------------------------------
// Per-pixel cosine sim, reduced to per-BLOCK partials (no global atomics).
// Prologue reduces blkmax (24 masks x 8 blocks) -> inv[m] in LDS.
// sim = (sp*sl + [argmax==lab]) / (sqrt(sp^2+1)*sqrt(sl^2+1)),
// sp/sl = sum_c sqrt(d) * inv[m]. argmax/lab come from the codes byte.
// grid: 1024 blocks x 256 (blocks 256b..256b+255 cover batch b).
// ---------------------------------------------------------------------------
__global__ __launch_bounds__(256) void k_final(const unsigned char* __restrict__ codes,
                                               const float* __restrict__ dbuf,
                                               const float* __restrict__ blkmax,
                                               float* __restrict__ psum,
                                               int* __restrict__ pfg) {
    __shared__ float inv[NM];
    if (threadIdx.x < NM) {
        const float* bm = blkmax + (threadIdx.x << 3);
        float v = 0.0f;
        #pragma unroll
        for (int s = 0; s < 8; ++s) v = fmaxf(v, bm[s]);
        inv[threadIdx.x] = 1.0f / (fminf(sqrtf(v), LIMITF) + EPSF);
    }
    __syncthreads();

    int b = blockIdx.x >> 8;                         // uniform per block
    int pix = ((blockIdx.x & 255) << 8) + threadIdx.x;

    int code = codes[(b << 16) + pix];
    int lv = code & 3;
    int am = code >> 2;

    float slab = 0.0f, spred = 0.0f;
    #pragma unroll
    for (int c = 0; c < 3; ++c) {
        int ml = b * 3 + c;
        float dl = dbuf[(((size_t)ml) << 16) + pix];
        slab += sqrtf(dl) * inv[ml];
        float dp = dbuf[(((size_t)(ml + 12)) << 16) + pix];
        spred += sqrtf(dp) * inv[ml + 12];
    }

    float dot = spred * slab + ((am == lv) ? 1.0f : 0.0f);
    float na = sqrtf(spred * spred + 1.0f);
    float nb = sqrtf(slab * slab + 1.0f);
    float sim = dot / (fmaxf(na, 1e-8f) * fmaxf(nb, 1e-8f));

    unsigned long long fg = __ballot(lv > 0);

    #pragma unroll
    for (int off = 32; off; off >>= 1)
        sim += __shfl_down(sim, off, 64);
    __shared__ float wsum[4];
    __shared__ int wfg[4];
    if ((threadIdx.x & 63) == 0) {
        wsum[threadIdx.x >> 6] = sim;
        wfg[threadIdx.x >> 6] = (fg != 0ULL) ? 1 : 0;
    }
    __syncthreads();
    if (threadIdx.x == 0) {
        psum[blockIdx.x] = wsum[0] + wsum[1] + wsum[2] + wsum[3];
        pfg[blockIdx.x] = wfg[0] | wfg[1] | wfg[2] | wfg[3];
    }
}

// ---------------------------------------------------------------------------
// Reduce 1024 block partials -> loss.
// ---------------------------------------------------------------------------
__global__ __launch_bounds__(256) void k_finalize(const float* __restrict__ psum,
                                                  const int* __restrict__ pfg,
                                                  float* __restrict__ out) {
    int t = threadIdx.x;
    int b = t >> 6, l = t & 63;
    int base = (b << 8) + l;
    float s = psum[base] + psum[base + 64] + psum[base + 128] + psum[base + 192];
    int f = pfg[base] | pfg[base + 64] | pfg[base + 128] | pfg[base + 192];
    #pragma unroll
    for (int off = 32; off; off >>= 1) {
        s += __shfl_down(s, off, 64);
        f |= __shfl_down(f, off, 64);
    }
    __shared__ float bsum[4];
    __shared__ int bfg[4];
    if (l == 0) { bsum[b] = s; bfg[b] = f; }
    __syncthreads();
    if (t == 0) {
        float loss = 0.0f;
        for (int bb = 0; bb < BB; ++bb) {
            float lb = 1.0f - bsum[bb] * (1.0f / (float)HW);
            if (bfg[bb]) loss += lb;
        }
        loss *= (1.0f / (float)BB);
        if (isnan(loss)) loss = 0.0f;
        else if (isinf(loss)) loss = (loss > 0.0f) ? 1.0f : 0.0f;
        out[0] = loss;
    }
}

extern "C" void kernel_launch(void* const* d_in, const int* in_sizes, int n_in,
                              void* d_out, int out_size, void* d_ws, size_t ws_size,
                              hipStream_t stream) {
    const float* pred = (const float*)d_in[0];   // [4,3,256,256] f32
    const int*   lab  = (const int*)d_in[1];     // [4,256,256] i32

    char* wsb = (char*)d_ws;
    float* dbuf   = (float*)wsb;                                  // 24*65536 f32 = 6 MB
    size_t off    = (size_t)NM * HW * sizeof(float);
    float* blkmax = (float*)(wsb + off);          off += 192 * sizeof(float);
    float* psum   = (float*)(wsb + off);          off += 1024 * sizeof(float);
    int*   pfg    = (int*)  (wsb + off);          off += 1024 * sizeof(int);
    unsigned char* codes = (unsigned char*)(wsb + off);           // 256 KB

    // Every scratch word is written before it is read — no memset needed.
    k_rowpass <<<BB * HH,  256, 0, stream>>>(pred, lab, dbuf, codes);
    k_colpass <<<NM * 8,   256, 0, stream>>>(dbuf, blkmax);
    k_final   <<<BB * 256, 256, 0, stream>>>(codes, dbuf, blkmax, psum, pfg);
    k_finalize<<<1,        256, 0, stream>>>(psum, pfg, (float*)d_out);
}

// Round 8
// 81.899 us; speedup vs baseline: 4.3355x; 1.1138x over previous
//
#include <hip/hip_runtime.h>
#include <hip/hip_bf16.h>

// Problem constants
#define HH 256
#define WW 256
#define BB 4
#define CC 3
#define HW 65536          // H*W
#define NM 24             // 2*B*C masks (0..11 lab, 12..23 pred)
#define BIGF 1e9f
#define LIMITF 331776.0f  // 576*576
#define EPSF 1e-5f

// R6 lesson: cooperative grid.sync() ~90us/sync at 1024 blocks — keep 4 launches.
// R7 lesson: 32-wide slab = 192 blocks/33KB LDS -> 7% occupancy + 319k LDS
// conflicts; and per-lane divergent window loops serialize ds_read latency
// (~120cy each). Fix: wave-uniform window offset loop, 8-wide slabs.

// ---------------------------------------------------------------------------
// Pass 1: row-wise squared distance to nearest zero, all 6 masks of one
// (batch,row) per block. Stores RAW d1 (bit-exact vs reference row pass)
// plus a per-pixel code byte (lab | argmax<<2) so k_final never re-reads
// pred/lab.
// grid: 4*256 blocks (b,row), 256 threads (col).
// ---------------------------------------------------------------------------
__global__ __launch_bounds__(256) void k_rowpass(const float* __restrict__ pred,
                                                 const int* __restrict__ lab,
                                                 float* __restrict__ dbuf,
                                                 unsigned char* __restrict__ codes) {
    int blk = blockIdx.x;
    int b = blk >> 8;
    int i = blk & 255;
    int j = threadIdx.x;

    int lv = lab[(b << 16) + (i << 8) + j];
    const float* pb = pred + (((size_t)(b * 3)) << 16) + (i << 8) + j;
    float p0 = pb[0];
    float p1 = pb[(size_t)1 << 16];
    float p2 = pb[(size_t)2 << 16];
    int am = 0; float v = p0;
    if (p1 > v) { am = 1; v = p1; }
    if (p2 > v) { am = 2; }

    codes[(b << 16) + (i << 8) + j] = (unsigned char)(lv | (am << 2));

    __shared__ unsigned long long zm[6][4];   // [mask][wave] zero-pixel bitmaps
    int w = threadIdx.x >> 6;
    #pragma unroll
    for (int c = 0; c < 3; ++c) {
        unsigned long long zl = __ballot(lv != c);
        unsigned long long zp = __ballot(am != c);
        if ((threadIdx.x & 63) == 0) { zm[c][w] = zl; zm[3 + c][w] = zp; }
    }
    __syncthreads();

    #pragma unroll
    for (int t = 0; t < 6; ++t) {
        int bestd = 512;  // sentinel > any possible distance (<=255)
        #pragma unroll
        for (int w2 = 0; w2 < 4; ++w2) {
            unsigned long long z = zm[t][w2];
            int base = w2 << 6;
            int rel = j - base;
            unsigned long long mle;   // bits at positions <= rel
            if (rel >= 63)      mle = ~0ULL;
            else if (rel < 0)   mle = 0ULL;
            else                mle = (2ULL << rel) - 1ULL;
            unsigned long long zl = z & mle;
            if (zl) {
                int p = base + 63 - __clzll(zl);
                int d = j - p;
                if (d < bestd) bestd = d;
            }
            unsigned long long zr = z & ~mle;
            if (zr) {
                int p = base + __ffsll(zr) - 1;
                int d = p - j;
                if (d < bestd) bestd = d;
            }
        }
        float d1 = (bestd >= 512) ? BIGF : (float)(bestd * bestd);
        int c = (t < 3) ? t : (t - 3);
        int m = ((t < 3) ? 0 : 12) + b * 3 + c;
        dbuf[(((size_t)m) << 16) + (i << 8) + j] = d1;
    }
}

// ---------------------------------------------------------------------------
// Pass 2: column min-plus d[i,j]=min_k d1[k,j]+(i-k)^2 with a WAVE-UNIFORM
// exact window. Rmax = wave-max of floor(sqrt(d1[i]))+1 (candidate k=i means
// no k beyond each lane's own radius can win; a uniform superset window is
// still exact — extra candidates only re-confirm the min). Uniform offset
// loop o in [-Rmax,+Rmax], 8 independent rows unrolled inside: 8 ds_reads in
// flight per iteration (no per-lane-divergent serialized chain), uniform-o
// addresses -> <=3-way bank aliasing. k clamped to [0,255] (duplicate
// candidates harmless); BIG -> Rmax=255 = exact full scan.
// One block owns 8 FULL columns (in-place safe). Stride-9 LDS pad.
// grid: 24*32 blocks, 256 threads.
// ---------------------------------------------------------------------------
__global__ __launch_bounds__(256) void k_colpass(float* __restrict__ dbuf,
                                                 float* __restrict__ blkmax) {
    int blk = blockIdx.x;
    int m = blk >> 5;
    int j0 = (blk & 31) << 3;
    __shared__ float tile[256 * 9];   // [row][jj], stride 9, 9 KB
    float* base = dbuf + (((size_t)m) << 16);

    // Stage 256x8 slab via float4 (2 per thread).
    #pragma unroll
    for (int it = 0; it < 2; ++it) {
        int f = (it << 8) + threadIdx.x;   // float4 index 0..511
        int row = f >> 1, half = f & 1;
        float4 v4 = *(const float4*)(base + (row << 8) + j0 + (half << 2));
        int lb = row * 9 + (half << 2);
        tile[lb + 0] = v4.x; tile[lb + 1] = v4.y;
        tile[lb + 2] = v4.z; tile[lb + 3] = v4.w;
    }
    __syncthreads();

    int jj = threadIdx.x & 7;
    int ib = threadIdx.x >> 3;   // 0..31

    float di[8], acc[8];
    float dmax = 0.0f;
    #pragma unroll
    for (int r = 0; r < 8; ++r) {
        di[r] = tile[(ib + (r << 5)) * 9 + jj];
        acc[r] = di[r];                  // k=i candidate
        dmax = fmaxf(dmax, di[r]);
    }
    // wave-wide max -> uniform window radius (xor-butterfly: all lanes get it)
    #pragma unroll
    for (int off = 32; off; off >>= 1)
        dmax = fmaxf(dmax, __shfl_xor(dmax, off, 64));
    int Rmax = (int)sqrtf(dmax) + 1;
    if (Rmax > 255) Rmax = 255;

    for (int o = -Rmax; o <= Rmax; ++o) {
        #pragma unroll
        for (int r = 0; r < 8; ++r) {
            int i = ib + (r << 5);
            int k = i + o;
            k = (k < 0) ? 0 : ((k > 255) ? 255 : k);
            float dk = (float)(k - i);
            acc[r] = fminf(acc[r], fmaf(dk, dk, tile[k * 9 + jj]));
        }
    }

    float lmax = 0.0f;
    #pragma unroll
    for (int r = 0; r < 8; ++r) {
        int i = ib + (r << 5);
        base[(i << 8) + j0 + jj] = acc[r];
        lmax = fmaxf(lmax, acc[r]);
    }

    #pragma unroll
    for (int off = 32; off; off >>= 1)
        lmax = fmaxf(lmax, __shfl_down(lmax, off, 64));
    __shared__ float wmax[4];
    if ((threadIdx.x & 63) == 0) wmax[threadIdx.x >> 6] = lmax;
    __syncthreads();
    if (threadIdx.x == 0)
        blkmax[blk] = fmaxf(fmaxf(wmax[0], wmax[1]), fmaxf(wmax[2], wmax[3]));
}

// ---------------------------------------------------------------------------
// Per-pixel cosine sim, reduced to per-BLOCK partials (no global atomics).
// Prologue reduces blkmax (24 masks x 32 blocks) -> inv[m] in LDS.
// sim = (sp*sl + [argmax==lab]) / (sqrt(sp^2+1)*sqrt(sl^2+1)),
// sp/sl = sum_c sqrt(d) * inv[m]; argmax/lab from the codes byte.
// grid: 1024 blocks x 256 (blocks 256b..256b+255 cover batch b).
// ---------------------------------------------------------------------------
__global__ __launch_bounds__(256) void k_final(const unsigned char* __restrict__ codes,
                                               const float* __restrict__ dbuf,
                                               const float* __restrict__ blkmax,
                                               float* __restrict__ psum,
                                               int* __restrict__ pfg) {
    __shared__ float inv[NM];
    if (threadIdx.x < NM) {
        const float* bm = blkmax + (threadIdx.x << 5);
        float v = 0.0f;
        #pragma unroll
        for (int s = 0; s < 32; ++s) v = fmaxf(v, bm[s]);
        inv[threadIdx.x] = 1.0f / (fminf(sqrtf(v), LIMITF) + EPSF);
    }
    __syncthreads();

    int b = blockIdx.x >> 8;                         // uniform per block
    int pix = ((blockIdx.x & 255) << 8) + threadIdx.x;

    int code = codes[(b << 16) + pix];
    int lv = code & 3;
    int am = code >> 2;

    float slab = 0.0f, spred = 0.0f;
    #pragma unroll
    for (int c = 0; c < 3; ++c) {
        int ml = b * 3 + c;
        float dl = dbuf[(((size_t)ml) << 16) + pix];
        slab += sqrtf(dl) * inv[ml];
        float dp = dbuf[(((size_t)(ml + 12)) << 16) + pix];
        spred += sqrtf(dp) * inv[ml + 12];
    }

    float dot = spred * slab + ((am == lv) ? 1.0f : 0.0f);
    float na = sqrtf(spred * spred + 1.0f);
    float nb = sqrtf(slab * slab + 1.0f);
    float sim = dot / (fmaxf(na, 1e-8f) * fmaxf(nb, 1e-8f));

    unsigned long long fg = __ballot(lv > 0);

    #pragma unroll
    for (int off = 32; off; off >>= 1)
        sim += __shfl_down(sim, off, 64);
    __shared__ float wsum[4];
    __shared__ int wfg[4];
    if ((threadIdx.x & 63) == 0) {
        wsum[threadIdx.x >> 6] = sim;
        wfg[threadIdx.x >> 6] = (fg != 0ULL) ? 1 : 0;
    }
    __syncthreads();
    if (threadIdx.x == 0) {
        psum[blockIdx.x] = wsum[0] + wsum[1] + wsum[2] + wsum[3];
        pfg[blockIdx.x] = wfg[0] | wfg[1] | wfg[2] | wfg[3];
    }
}

// ---------------------------------------------------------------------------
// Reduce 1024 block partials -> loss.
// ---------------------------------------------------------------------------
__global__ __launch_bounds__(256) void k_finalize(const float* __restrict__ psum,
                                                  const int* __restrict__ pfg,
                                                  float* __restrict__ out) {
    int t = threadIdx.x;
    int b = t >> 6, l = t & 63;
    int base = (b << 8) + l;
    float s = psum[base] + psum[base + 64] + psum[base + 128] + psum[base + 192];
    int f = pfg[base] | pfg[base + 64] | pfg[base + 128] | pfg[base + 192];
    #pragma unroll
    for (int off = 32; off; off >>= 1) {
        s += __shfl_down(s, off, 64);
        f |= __shfl_down(f, off, 64);
    }
    __shared__ float bsum[4];
    __shared__ int bfg[4];
    if (l == 0) { bsum[b] = s; bfg[b] = f; }
    __syncthreads();
    if (t == 0) {
        float loss = 0.0f;
        for (int bb = 0; bb < BB; ++bb) {
            float lb = 1.0f - bsum[bb] * (1.0f / (float)HW);
            if (bfg[bb]) loss += lb;
        }
        loss *= (1.0f / (float)BB);
        if (isnan(loss)) loss = 0.0f;
        else if (isinf(loss)) loss = (loss > 0.0f) ? 1.0f : 0.0f;
        out[0] = loss;
    }
}

extern "C" void kernel_launch(void* const* d_in, const int* in_sizes, int n_in,
                              void* d_out, int out_size, void* d_ws, size_t ws_size,
                              hipStream_t stream) {
    const float* pred = (const float*)d_in[0];   // [4,3,256,256] f32
    const int*   lab  = (const int*)d_in[1];     // [4,256,256] i32

    char* wsb = (char*)d_ws;
    float* dbuf   = (float*)wsb;                                  // 24*65536 f32 = 6 MB
    size_t off    = (size_t)NM * HW * sizeof(float);
    float* blkmax = (float*)(wsb + off);          off += 768 * sizeof(float);
    float* psum   = (float*)(wsb + off);          off += 1024 * sizeof(float);
    int*   pfg    = (int*)  (wsb + off);          off += 1024 * sizeof(int);
    unsigned char* codes = (unsigned char*)(wsb + off);           // 256 KB

    // Every scratch word is written before it is read — no memset needed.
    k_rowpass <<<BB * HH,  256, 0, stream>>>(pred, lab, dbuf, codes);
    k_colpass <<<NM * 32,  256, 0, stream>>>(dbuf, blkmax);
    k_final   <<<BB * 256, 256, 0, stream>>>(codes, dbuf, blkmax, psum, pfg);
    k_finalize<<<1,        256, 0, stream>>>(psum, pfg, (float*)d_out);
}

// Round 9
// 81.575 us; speedup vs baseline: 4.3527x; 1.0040x over previous
//
#include <hip/hip_runtime.h>
#include <hip/hip_bf16.h>

// Problem constants
#define HH 256
#define WW 256
#define BB 4
#define CC 3
#define HW 65536          // H*W
#define NM 24             // 2*B*C masks (0..11 lab, 12..23 pred)
#define BIGF 1e9f
#define LIMITF 331776.0f  // 576*576
#define EPSF 1e-5f

// R6 lesson: cooperative grid.sync() ~90us/sync at 1024 blocks — keep 4 launches.
// R7 lesson: 33KB-LDS blocks -> 7% occupancy + per-lane divergent window loops
// serialize ds_read latency. R8 fix: wave-uniform window. R9: guard rows kill
// the per-candidate clamp; dk^2 becomes a wave-scalar add (bit-identical).

// ---------------------------------------------------------------------------
// Pass 1: row-wise squared distance to nearest zero, all 6 masks of one
// (batch,row) per block. Stores RAW d1 (bit-exact vs reference row pass)
// plus a per-pixel code byte (lab | argmax<<2) so k_final never re-reads
// pred/lab.
// grid: 4*256 blocks (b,row), 256 threads (col).
// ---------------------------------------------------------------------------
__global__ __launch_bounds__(256) void k_rowpass(const float* __restrict__ pred,
                                                 const int* __restrict__ lab,
                                                 float* __restrict__ dbuf,
                                                 unsigned char* __restrict__ codes) {
    int blk = blockIdx.x;
    int b = blk >> 8;
    int i = blk & 255;
    int j = threadIdx.x;

    int lv = lab[(b << 16) + (i << 8) + j];
    const float* pb = pred + (((size_t)(b * 3)) << 16) + (i << 8) + j;
    float p0 = pb[0];
    float p1 = pb[(size_t)1 << 16];
    float p2 = pb[(size_t)2 << 16];
    int am = 0; float v = p0;
    if (p1 > v) { am = 1; v = p1; }
    if (p2 > v) { am = 2; }

    codes[(b << 16) + (i << 8) + j] = (unsigned char)(lv | (am << 2));

    __shared__ unsigned long long zm[6][4];   // [mask][wave] zero-pixel bitmaps
    int w = threadIdx.x >> 6;
    #pragma unroll
    for (int c = 0; c < 3; ++c) {
        unsigned long long zl = __ballot(lv != c);
        unsigned long long zp = __ballot(am != c);
        if ((threadIdx.x & 63) == 0) { zm[c][w] = zl; zm[3 + c][w] = zp; }
    }
    __syncthreads();

    #pragma unroll
    for (int t = 0; t < 6; ++t) {
        int bestd = 512;  // sentinel > any possible distance (<=255)
        #pragma unroll
        for (int w2 = 0; w2 < 4; ++w2) {
            unsigned long long z = zm[t][w2];
            int base = w2 << 6;
            int rel = j - base;
            unsigned long long mle;   // bits at positions <= rel
            if (rel >= 63)      mle = ~0ULL;
            else if (rel < 0)   mle = 0ULL;
            else                mle = (2ULL << rel) - 1ULL;
            unsigned long long zl = z & mle;
            if (zl) {
                int p = base + 63 - __clzll(zl);
                int d = j - p;
                if (d < bestd) bestd = d;
            }
            unsigned long long zr = z & ~mle;
            if (zr) {
                int p = base + __ffsll(zr) - 1;
                int d = p - j;
                if (d < bestd) bestd = d;
            }
        }
        float d1 = (bestd >= 512) ? BIGF : (float)(bestd * bestd);
        int c = (t < 3) ? t : (t - 3);
        int m = ((t < 3) ? 0 : 12) + b * 3 + c;
        dbuf[(((size_t)m) << 16) + (i << 8) + j] = d1;
    }
}

// ---------------------------------------------------------------------------
// Pass 2: column min-plus d[i,j]=min_k d1[k,j]+(i-k)^2, wave-uniform exact
// window (Rmax = wave-max floor(sqrt(d1[i]))+1; superset window is exact).
// Tile has 32 BIG guard rows on each side (k in [-32,287]); guard candidates
// are >= 1e9 + o^2 and can never beat a real candidate (fast path requires
// dmax < 1024), so for Rmax<=32 NO clamping is needed and dk=o exactly:
// fma(dk,dk,fk) == RN(o^2+fk) == add(o2,fk) with wave-scalar o2 — inner loop
// is ds_read+add+min per row, bit-identical to reference. Rmax>32 (BIG rows
// present) takes the clamped slow path (exact full logic).
// One block owns 8 FULL columns (in-place safe). Stride-9 LDS pad.
// grid: 24*32 blocks, 256 threads.
// ---------------------------------------------------------------------------
__global__ __launch_bounds__(256) void k_colpass(float* __restrict__ dbuf,
                                                 float* __restrict__ blkmax) {
    int blk = blockIdx.x;
    int m = blk >> 5;
    int j0 = (blk & 31) << 3;
    __shared__ float tile[320 * 9];   // rows 0..319 = k -32..287, stride 9 (11.25 KB)
    float* base = dbuf + (((size_t)m) << 16);

    // Guard rows (k=-32..-1 and k=256..287) = BIG. 2*32 rows*8 cols, 2/thread.
    {
        int t = threadIdx.x;
        int gr = t >> 3, gc = t & 7;          // 32 rows x 8 cols
        tile[gr * 9 + gc] = BIGF;             // k = -32..-1
        tile[(288 + gr) * 9 + gc] = BIGF;     // k = 256..287
    }
    // Stage 256x8 slab via float4 (2 per thread) into rows 32..287.
    #pragma unroll
    for (int it = 0; it < 2; ++it) {
        int f = (it << 8) + threadIdx.x;   // float4 index 0..511
        int row = f >> 1, half = f & 1;
        float4 v4 = *(const float4*)(base + (row << 8) + j0 + (half << 2));
        int lb = (row + 32) * 9 + (half << 2);
        tile[lb + 0] = v4.x; tile[lb + 1] = v4.y;
        tile[lb + 2] = v4.z; tile[lb + 3] = v4.w;
    }
    __syncthreads();

    int jj = threadIdx.x & 7;
    int ib = threadIdx.x >> 3;   // 0..31

    float acc[8];
    float dmax = 0.0f;
    #pragma unroll
    for (int r = 0; r < 8; ++r) {
        acc[r] = tile[(ib + (r << 5) + 32) * 9 + jj];   // k=i candidate
        dmax = fmaxf(dmax, acc[r]);
    }
    // wave-wide max -> uniform window radius (xor-butterfly: all lanes get it)
    #pragma unroll
    for (int off = 32; off; off >>= 1)
        dmax = fmaxf(dmax, __shfl_xor(dmax, off, 64));
    int Rmax = (int)sqrtf(dmax) + 1;
    if (Rmax > 255) Rmax = 255;

    if (Rmax <= 32) {
        // Fast path: guards cover k=i+o fully; dk^2 = o^2 wave-scalar.
        for (int o = -Rmax; o <= Rmax; ++o) {
            float o2 = (float)(o * o);
            #pragma unroll
            for (int r = 0; r < 8; ++r)
                acc[r] = fminf(acc[r], o2 + tile[(ib + (r << 5) + 32 + o) * 9 + jj]);
        }
    } else {
        // Slow path (BIG rows in wave): clamped candidates, exact full logic.
        for (int o = -Rmax; o <= Rmax; ++o) {
            #pragma unroll
            for (int r = 0; r < 8; ++r) {
                int i = ib + (r << 5);
                int k = i + o;
                k = (k < 0) ? 0 : ((k > 255) ? 255 : k);
                float dk = (float)(k - i);
                acc[r] = fminf(acc[r], fmaf(dk, dk, tile[(k + 32) * 9 + jj]));
            }
        }
    }

    float lmax = 0.0f;
    #pragma unroll
    for (int r = 0; r < 8; ++r) {
        int i = ib + (r << 5);
        base[(i << 8) + j0 + jj] = acc[r];
        lmax = fmaxf(lmax, acc[r]);
    }

    #pragma unroll
    for (int off = 32; off; off >>= 1)
        lmax = fmaxf(lmax, __shfl_down(lmax, off, 64));
    __shared__ float wmax[4];
    if ((threadIdx.x & 63) == 0) wmax[threadIdx.x >> 6] = lmax;
    __syncthreads();
    if (threadIdx.x == 0)
        blkmax[blk] = fmaxf(fmaxf(wmax[0], wmax[1]), fmaxf(wmax[2], wmax[3]));
}

// ---------------------------------------------------------------------------
// Per-pixel cosine sim, reduced to per-BLOCK partials (no global atomics).
// Prologue reduces blkmax (24 masks x 32 blocks) -> inv[m] in LDS.
// sim = (sp*sl + [argmax==lab]) / (sqrt(sp^2+1)*sqrt(sl^2+1)),
// sp/sl = sum_c sqrt(d) * inv[m]; argmax/lab from the codes byte.
// grid: 1024 blocks x 256 (blocks 256b..256b+255 cover batch b).
// ---------------------------------------------------------------------------
__global__ __launch_bounds__(256) void k_final(const unsigned char* __restrict__ codes,
                                               const float* __restrict__ dbuf,
                                               const float* __restrict__ blkmax,
                                               float* __restrict__ psum,
                                               int* __restrict__ pfg) {
    __shared__ float inv[NM];
    if (threadIdx.x < NM) {
        const float* bm = blkmax + (threadIdx.x << 5);
        float v = 0.0f;
        #pragma unroll
        for (int s = 0; s < 32; ++s) v = fmaxf(v, bm[s]);
        inv[threadIdx.x] = 1.0f / (fminf(sqrtf(v), LIMITF) + EPSF);
    }
    __syncthreads();

    int b = blockIdx.x >> 8;                         // uniform per block
    int pix = ((blockIdx.x & 255) << 8) + threadIdx.x;

    int code = codes[(b << 16) + pix];
    int lv = code & 3;
    int am = code >> 2;

    float slab = 0.0f, spred = 0.0f;
    #pragma unroll
    for (int c = 0; c < 3; ++c) {
        int ml = b * 3 + c;
        float dl = dbuf[(((size_t)ml) << 16) + pix];
        slab += sqrtf(dl) * inv[ml];
        float dp = dbuf[(((size_t)(ml + 12)) << 16) + pix];
        spred += sqrtf(dp) * inv[ml + 12];
    }

    float dot = spred * slab + ((am == lv) ? 1.0f : 0.0f);
    float na = sqrtf(spred * spred + 1.0f);
    float nb = sqrtf(slab * slab + 1.0f);
    float sim = dot / (fmaxf(na, 1e-8f) * fmaxf(nb, 1e-8f));

    unsigned long long fg = __ballot(lv > 0);

    #pragma unroll
    for (int off = 32; off; off >>= 1)
        sim += __shfl_down(sim, off, 64);
    __shared__ float wsum[4];
    __shared__ int wfg[4];
    if ((threadIdx.x & 63) == 0) {
        wsum[threadIdx.x >> 6] = sim;
        wfg[threadIdx.x >> 6] = (fg != 0ULL) ? 1 : 0;
    }
    __syncthreads();
    if (threadIdx.x == 0) {
        psum[blockIdx.x] = wsum[0] + wsum[1] + wsum[2] + wsum[3];
        pfg[blockIdx.x] = wfg[0] | wfg[1] | wfg[2] | wfg[3];
    }
}

// ---------------------------------------------------------------------------
// Reduce 1024 block partials -> loss.
// ---------------------------------------------------------------------------
__global__ __launch_bounds__(256) void k_finalize(const float* __restrict__ psum,
                                                  const int* __restrict__ pfg,
                                                  float* __restrict__ out) {
    int t = threadIdx.x;
    int b = t >> 6, l = t & 63;
    int base = (b << 8) + l;
    float s = psum[base] + psum[base + 64] + psum[base + 128] + psum[base + 192];
    int f = pfg[base] | pfg[base + 64] | pfg[base + 128] | pfg[base + 192];
    #pragma unroll
    for (int off = 32; off; off >>= 1) {
        s += __shfl_down(s, off, 64);
        f |= __shfl_down(f, off, 64);
    }
    __shared__ float bsum[4];
    __shared__ int bfg[4];
    if (l == 0) { bsum[b] = s; bfg[b] = f; }
    __syncthreads();
    if (t == 0) {
        float loss = 0.0f;
        for (int bb = 0; bb < BB; ++bb) {
            float lb = 1.0f - bsum[bb] * (1.0f / (float)HW);
            if (bfg[bb]) loss += lb;
        }
        loss *= (1.0f / (float)BB);
        if (isnan(loss)) loss = 0.0f;
        else if (isinf(loss)) loss = (loss > 0.0f) ? 1.0f : 0.0f;
        out[0] = loss;
    }
}

extern "C" void kernel_launch(void* const* d_in, const int* in_sizes, int n_in,
                              void* d_out, int out_size, void* d_ws, size_t ws_size,
                              hipStream_t stream) {
    const float* pred = (const float*)d_in[0];   // [4,3,256,256] f32
    const int*   lab  = (const int*)d_in[1];     // [4,256,256] i32

    char* wsb = (char*)d_ws;
    float* dbuf   = (float*)wsb;                                  // 24*65536 f32 = 6 MB
    size_t off    = (size_t)NM * HW * sizeof(float);
    float* blkmax = (float*)(wsb + off);          off += 768 * sizeof(float);
    float* psum   = (float*)(wsb + off);          off += 1024 * sizeof(float);
    int*   pfg    = (int*)  (wsb + off);          off += 1024 * sizeof(int);
    unsigned char* codes = (unsigned char*)(wsb + off);           // 256 KB

    // Every scratch word is written before it is read — no memset needed.
    k_rowpass <<<BB * HH,  256, 0, stream>>>(pred, lab, dbuf, codes);
    k_colpass <<<NM * 32,  256, 0, stream>>>(dbuf, blkmax);
    k_final   <<<BB * 256, 256, 0, stream>>>(codes, dbuf, blkmax, psum, pfg);
    k_finalize<<<1,        256, 0, stream>>>(psum, pfg, (float*)d_out);
}